// Round 13
// baseline (2831.495 us; speedup 1.0000x reference)
//
#include <hip/hip_runtime.h>

// Pool_FPS: furthest point sampling (B=8, N=32768, K=1024) + gather (C=128).
//
// ROUND-12 LESSON: sc0 probes returned STALE lines (+5.4MB FETCH, slower):
// agent(sc1) stores from remote XCDs bypass but do NOT invalidate a remote
// XCD-L2's cached copy. => the 8 workers of a batch were NOT co-XCD under
// b=bid&7, i.e. the coop dispatcher maps blocks to XCDs in CHUNKS
// (blocks 0-7 -> XCD0, ...), not round-robin. Also retro-explains R8's
// deadlock (sc0-only spin across XCDs never sees the store).
// THIS ROUND: single-variable experiment - SWAP THE MAPPING:
//     b = bid >> 3 (batch = chunk of 8 consecutive blocks -> one XCD)
//     blk = bid & 7
// Under chunked dispatch all 8 workers of a batch share an XCD: wg-scope
// stores land in the SHARED XCD-L2, sc0 probes read the same L2 -> fresh
// tag in ~300cy instead of LLC round trips. Everything else is identical
// to R12; the dual-path (wg+agent store, sc0+agent poll) protocol remains
// deadlock-proof under ANY placement.
//
// Protocol (proven bit-exact R7-R12): u64 [val:32|tag:10|n:15] parity slots,
// one 128B line per (parity,batch,worker), winner coords ride in words 1-3
// of the slot line (tagged), relaxed stores, tag==t proves freshness.
//
// Exactness: d = ((dx*dx+dy*dy)+dz*dz), rn ops, no fma contraction; argmax
// tie-break = smallest global index at every reduce level. idx[0]=0.
// Replay-safe: slot tags zeroed via hipMemsetAsync each launch.

#define BATCH 8
#define NPTS 32768
#define KSEL 1024
#define CFEAT 128
#define WPB 8                    // worker blocks per batch
#define LOCN (NPTS / WPB)        // 4096 points per block
#define TPB 512                  // 8 points per thread
#define PPT 8
#define NWAVE (TPB / 64)         // 8 waves

typedef unsigned long long u64;

#define AT_ST(p, v) __hip_atomic_store((p), (v), __ATOMIC_RELAXED, __HIP_MEMORY_SCOPE_AGENT)
#define AT_LD(p)    __hip_atomic_load((p), __ATOMIC_RELAXED, __HIP_MEMORY_SCOPE_AGENT)
#define WG_ST(p, v) __hip_atomic_store((p), (v), __ATOMIC_RELAXED, __HIP_MEMORY_SCOPE_WORKGROUP)
#define TAG(v)      ((int)(((v) >> 15) & 1023))

// sc0 load: bypass L1, read this XCD's L2. Only ever the FAST probe of the
// hybrid poll - never the sole exit path (R8 lesson).
__device__ __forceinline__ u64 ld_sc0(const u64* p) {
    u64 v;
    asm volatile("global_load_dwordx2 %0, %1, off sc0\n\ts_waitcnt vmcnt(0)"
                 : "=v"(v) : "v"(p) : "memory");
    return v;
}

__global__ void
__attribute__((amdgpu_flat_work_group_size(TPB, TPB)))
fps_kernel(const float* __restrict__ xyz, char* __restrict__ ws) {
    int* idxbuf = (int*)ws;                     // [BATCH*KSEL] 32KB
    u64* slots  = (u64*)(ws + 32768);           // [2][BATCH][WPB][16] 16KB

    __shared__ float4 lx4[LOCN / 4], ly4[LOCN / 4], lz4[LOCN / 4];  // 48KB mirror
    __shared__ float  swd[NWAVE];
    __shared__ int    swn[NWAVE];
    __shared__ float  scen[3];

    const int bid  = blockIdx.x;
    const int b    = bid >> 3;                  // batch  (CHUNK -> one XCD)
    const int blk  = bid & 7;                   // worker id within batch
    const int tid  = threadIdx.x;
    const int lane = tid & 63;
    const int wid  = tid >> 6;

    const float* Xp = xyz + (size_t)b * 3 * NPTS;
    const float* Yp = Xp + NPTS;
    const float* Zp = Xp + 2 * NPTS;
    const float4* X4 = (const float4*)Xp;
    const float4* Y4 = (const float4*)Yp;
    const float4* Z4 = (const float4*)Zp;

    // own 8 consecutive points: global idx = blk*LOCN + tid*8 + e
    const int f4 = blk * (LOCN / 4) + 2 * tid;
    const float4 xa = X4[f4], xb = X4[f4 + 1];
    const float4 ya = Y4[f4], yb = Y4[f4 + 1];
    const float4 za = Z4[f4], zb = Z4[f4 + 1];
    lx4[2 * tid] = xa; lx4[2 * tid + 1] = xb;
    ly4[2 * tid] = ya; ly4[2 * tid + 1] = yb;
    lz4[2 * tid] = za; lz4[2 * tid + 1] = zb;
    float xs[PPT] = {xa.x, xa.y, xa.z, xa.w, xb.x, xb.y, xb.z, xb.w};
    float ys[PPT] = {ya.x, ya.y, ya.z, ya.w, yb.x, yb.y, yb.z, yb.w};
    float zs[PPT] = {za.x, za.y, za.z, za.w, zb.x, zb.y, zb.z, zb.w};
    float ds[PPT];
#pragma unroll
    for (int e = 0; e < PPT; ++e) ds[e] = __builtin_inff();

    if (blk == 0 && tid == 0) idxbuf[(size_t)b * KSEL] = 0;   // idx[0] = 0
    float cx = Xp[0], cy = Yp[0], cz = Zp[0];
    __syncthreads();   // lx4/ly4/lz4 mirror complete

    for (int t = 1; t < KSEL; ++t) {
        // ---- update ds, thread-local argmax (8 pts, all in regs) ----
        float bd = -__builtin_inff();
        int   be = 0;
#pragma unroll
        for (int e = 0; e < PPT; ++e) {
            const float dx = xs[e] - cx;
            const float dy = ys[e] - cy;
            const float dz = zs[e] - cz;
            // exact: ((dx*dx + dy*dy) + dz*dz), rn, no fma contraction
            const float d = __fadd_rn(__fadd_rn(__fmul_rn(dx, dx), __fmul_rn(dy, dy)),
                                      __fmul_rn(dz, dz));
            const float nd = fminf(ds[e], d);
            ds[e] = nd;
            const bool gt = nd > bd;        // strict > keeps smallest e
            bd = gt ? nd : bd;
            be = gt ? e : be;
        }
        int bn = tid * PPT + be;            // block-local point index (0..4095)
        // ---- wave argmax (max d, tie -> min index) ----
#pragma unroll
        for (int off = 32; off >= 1; off >>= 1) {
            const float od = __shfl_xor(bd, off);
            const int   on = __shfl_xor(bn, off);
            if (od > bd || (od == bd && on < bn)) { bd = od; bn = on; }
        }
        if (lane == 0) { swd[wid] = bd; swn[wid] = bn; }
        __syncthreads();                    // barrier #1

        if (wid == 0) {
            // ---- block reduce over 8 wave slots (dup-safe: lane&7) ----
            float rd = swd[lane & 7];
            int   rn = swn[lane & 7];
#pragma unroll
            for (int off = 4; off >= 1; off >>= 1) {
                const float od = __shfl_xor(rd, off);
                const int   on = __shfl_xor(rn, off);
                if (od > rd || (od == rd && on < rn)) { rd = od; rn = on; }
            }
            u64* base = slots + ((size_t)((t & 1) * BATCH + b)) * (WPB * 16);
            if (lane == 0) {
                const int gn = blk * LOCN + rn;          // batch-global index
                const float wx = ((const float*)lx4)[rn];
                const float wy = ((const float*)ly4)[rn];
                const float wz = ((const float*)lz4)[rn];
                const u64 tg = ((u64)(t & 1023) << 15);
                const u64 w0 = ((u64)__float_as_uint(rd) << 32) | tg | (u64)gn;
                const u64 w1 = ((u64)__float_as_uint(wx) << 32) | tg;
                const u64 w2 = ((u64)__float_as_uint(wy) << 32) | tg;
                const u64 w3 = ((u64)__float_as_uint(wz) << 32) | tg;
                u64* myline = base + blk * 16;           // own 128B line
                // dual publish: local-XCD-L2 copy (fast), then LLC copy (sure)
                WG_ST(myline + 0, w0); WG_ST(myline + 1, w1);
                WG_ST(myline + 2, w2); WG_ST(myline + 3, w3);
                AT_ST(myline + 0, w0); AT_ST(myline + 1, w1);
                AT_ST(myline + 2, w2); AT_ST(myline + 3, w3);
            }
            // ---- hybrid poll: lane L -> word ((L>>3)&3) of block (L&7);
            //      sc0 probe (local XCD L2) alternated with agent load (LLC) ----
            u64* sp = base + (lane & 7) * 16 + ((lane >> 3) & 3);
            u64 v;
            for (;;) {
                const u64 vf = ld_sc0(sp);
                if (__all(TAG(vf) == t)) { v = vf; break; }
                const u64 va = AT_LD(sp);
                if (__all(TAG(va) == t)) { v = va; break; }
            }
            // ---- winner among 8 blocks (word0 lives in lanes 0..7) ----
            float bdv = -__builtin_inff();
            int   bnv = 0x7FFFFFFF;
            int   wsel = 0;
#pragma unroll
            for (int k = 0; k < 8; ++k) {
                const u64 vk = __shfl(v, k);
                const float dk = __uint_as_float((unsigned)(vk >> 32));
                const int   nk = (int)(vk & 32767);
                const bool better = (dk > bdv) || (dk == bdv && nk < bnv);
                bdv  = better ? dk : bdv;
                bnv  = better ? nk : bnv;
                wsel = better ? k : wsel;
            }
            const u64 vx = __shfl(v, 8 + wsel);    // word1 of winner block
            const u64 vy = __shfl(v, 16 + wsel);   // word2
            const u64 vz = __shfl(v, 24 + wsel);   // word3
            if (lane == 0) {
                scen[0] = __uint_as_float((unsigned)(vx >> 32));
                scen[1] = __uint_as_float((unsigned)(vy >> 32));
                scen[2] = __uint_as_float((unsigned)(vz >> 32));
                if (blk == 0) idxbuf[(size_t)b * KSEL + t] = bnv;
            }
        }
        __syncthreads();                    // barrier #2
        cx = scen[0]; cy = scen[1]; cz = scen[2];
    }
}

__global__ void gather_kernel(const float* __restrict__ xyz,
                              const float* __restrict__ feat,
                              const int* __restrict__ idxbuf,
                              float* __restrict__ out) {
    const int SN = BATCH * 3 * KSEL;                  // 24576
    const int total = SN + BATCH * CFEAT * KSEL;      // 1073152
    const int i = blockIdx.x * blockDim.x + threadIdx.x;
    if (i >= total) return;
    if (i < SN) {
        const int b = i / (3 * KSEL);
        const int r = i - b * 3 * KSEL;
        const int c = r / KSEL;
        const int k = r - c * KSEL;
        const int n = idxbuf[b * KSEL + k];
        out[i] = xyz[((size_t)b * 3 + c) * NPTS + n];
    } else {
        const int i2 = i - SN;
        const int b = i2 / (CFEAT * KSEL);
        const int r = i2 - b * CFEAT * KSEL;
        const int c = r / KSEL;
        const int k = r - c * KSEL;
        const int n = idxbuf[b * KSEL + k];
        out[SN + i2] = feat[((size_t)b * CFEAT + c) * NPTS + n];
    }
}

extern "C" void kernel_launch(void* const* d_in, const int* in_sizes, int n_in,
                              void* d_out, int out_size, void* d_ws, size_t ws_size,
                              hipStream_t stream) {
    const float* xyz  = (const float*)d_in[0];
    const float* feat = (const float*)d_in[1];
    float* out = (float*)d_out;
    char* ws = (char*)d_ws;
    // ws layout: [0,32KB) idxbuf | [32KB, +16KB) u64 slots [2][8][8][16]

    // zero slot tags every call (tag 0 never matches t>=1) — replay-safe
    hipMemsetAsync(ws + 32768, 0, 2 * BATCH * WPB * 16 * sizeof(u64), stream);

    void* args[] = {(void*)&xyz, (void*)&ws};
    hipLaunchCooperativeKernel((const void*)fps_kernel,
                               dim3(BATCH * WPB), dim3(TPB), args, 0, stream);

    int* idxbuf = (int*)d_ws;
    const int total = BATCH * 3 * KSEL + BATCH * CFEAT * KSEL;  // 1073152
    gather_kernel<<<(total + 255) / 256, 256, 0, stream>>>(xyz, feat, idxbuf, out);
}

// Round 14
// 2465.674 us; speedup vs baseline: 1.1484x; 1.1484x over previous
//
#include <hip/hip_runtime.h>

// Pool_FPS: furthest point sampling (B=8, N=32768, K=1024) + gather (C=128).
//
// ROUND 8/12/13 VERDICT: all XCD-local (sc0/wg-scope) rendezvous variants are
// unsound: wg-scope stores stay in the writer CU's L1 (not written through to
// XCD-L2), so sc0 probes always read stale/miss (R13: FETCH 34MB of 128B line
// refetches). Agent(sc1)-scope relaxed atomics at the LLC are the ONLY proven
// cross-block path (R7-R10, bit-exact). R10 = best: 2.25us/iter, sync ~1.9us.
// THIS ROUND: shrink LOCAL orchestration around the irreducible LLC trip:
//  (a) PER-WAVE publish (64 slots/batch = 8 blk x 8 waves): each wave stores
//      its wave-argmax right after its bfly -> no barrier#1, no block reduce,
//      publish starts ~350cy earlier.
//  (b) wave0-of-block polls all 64 slots: lane L <-> slot L, ONE
//      global_load_dwordx2 per probe (4-deep pipelined, proven R10), then a
//      6-level bfly -> winner. Still 8 pollers/batch (R9/R10-proven level).
//  (c) LDS-flag release replaces barrier#2: wave0 writes {t|winner} to one
//      LDS u64; other waves spin on it (intra-CU, no fabric). Max drift = 1
//      iteration; parity slots protect exactly that (same R7-R10 invariant:
//      publish(t+1) requires LDS-release(t) which requires wave0 detected ALL
//      64 slots at t, i.e. every wave globally published t).
//
// Exactness: d = ((dx*dx+dy*dy)+dz*dz), rn ops, no fma contraction; argmax
// tie-break = smallest global index at every reduce level (wave bfly keeps
// min-n; cross-slot bfly keeps min-n). idx[0]=0. Bit-exact R1-R13.
// Replay-safe: slot tags zeroed via hipMemsetAsync (tag 0 != t>=1); LDS flag
// initialized before the loop.

#define BATCH 8
#define NPTS 32768
#define KSEL 1024
#define CFEAT 128
#define WPB 8                    // worker blocks per batch
#define LOCN (NPTS / WPB)        // 4096 points per block
#define TPB 512                  // 8 points per thread
#define PPT 8
#define NWAVE (TPB / 64)         // 8 waves
#define SSTRIDE 4                // u64s per slot (32B spacing, 16 lines/batch)

typedef unsigned long long u64;

#define AT_ST(p, v) __hip_atomic_store((p), (v), __ATOMIC_RELAXED, __HIP_MEMORY_SCOPE_AGENT)
#define AT_LD(p)    __hip_atomic_load((p), __ATOMIC_RELAXED, __HIP_MEMORY_SCOPE_AGENT)
#define LDS_ST(p, v) __hip_atomic_store((p), (v), __ATOMIC_RELAXED, __HIP_MEMORY_SCOPE_WORKGROUP)
#define LDS_LD(p)    __hip_atomic_load((p), __ATOMIC_RELAXED, __HIP_MEMORY_SCOPE_WORKGROUP)
#define TAG(v)      ((int)(((v) >> 15) & 1023))

__global__ void
__attribute__((amdgpu_flat_work_group_size(TPB, TPB)))
fps_kernel(const float* __restrict__ xyz, char* __restrict__ ws) {
    int* idxbuf = (int*)ws;                     // [BATCH*KSEL] 32KB
    u64* slots  = (u64*)(ws + 32768);           // [2][BATCH][64][SSTRIDE] 32KB

    __shared__ u64 swin;                        // {t:32 | winner n:32}

    const int bid  = blockIdx.x;
    const int b    = bid & 7;                   // batch
    const int blk  = bid >> 3;                  // worker id within batch
    const int tid  = threadIdx.x;
    const int lane = tid & 63;
    const int wid  = tid >> 6;

    const float* Xp = xyz + (size_t)b * 3 * NPTS;
    const float* Yp = Xp + NPTS;
    const float* Zp = Xp + 2 * NPTS;
    const float4* X4 = (const float4*)Xp;
    const float4* Y4 = (const float4*)Yp;
    const float4* Z4 = (const float4*)Zp;

    // own 8 consecutive points: global idx = blk*LOCN + tid*8 + e
    const int f4 = blk * (LOCN / 4) + 2 * tid;
    const float4 xa = X4[f4], xb = X4[f4 + 1];
    const float4 ya = Y4[f4], yb = Y4[f4 + 1];
    const float4 za = Z4[f4], zb = Z4[f4 + 1];
    float xs[PPT] = {xa.x, xa.y, xa.z, xa.w, xb.x, xb.y, xb.z, xb.w};
    float ys[PPT] = {ya.x, ya.y, ya.z, ya.w, yb.x, yb.y, yb.z, yb.w};
    float zs[PPT] = {za.x, za.y, za.z, za.w, zb.x, zb.y, zb.z, zb.w};
    float ds[PPT];
#pragma unroll
    for (int e = 0; e < PPT; ++e) ds[e] = __builtin_inff();

    if (blk == 0 && tid == 0) idxbuf[(size_t)b * KSEL] = 0;   // idx[0] = 0
    if (tid == 0) LDS_ST(&swin, 0);
    float cx = Xp[0], cy = Yp[0], cz = Zp[0];
    __syncthreads();   // swin init visible

    for (int t = 1; t < KSEL; ++t) {
        // ---- update ds, thread-local argmax (8 pts, all in regs) ----
        float bd = -__builtin_inff();
        int   be = 0;
#pragma unroll
        for (int e = 0; e < PPT; ++e) {
            const float dx = xs[e] - cx;
            const float dy = ys[e] - cy;
            const float dz = zs[e] - cz;
            // exact: ((dx*dx + dy*dy) + dz*dz), rn, no fma contraction
            const float d = __fadd_rn(__fadd_rn(__fmul_rn(dx, dx), __fmul_rn(dy, dy)),
                                      __fmul_rn(dz, dz));
            const float nd = fminf(ds[e], d);
            ds[e] = nd;
            const bool gt = nd > bd;        // strict > keeps smallest e
            bd = gt ? nd : bd;
            be = gt ? e : be;
        }
        int bn = blk * LOCN + tid * PPT + be;   // batch-global index (15 bits)
        // ---- wave argmax (max d, tie -> min index) ----
#pragma unroll
        for (int off = 32; off >= 1; off >>= 1) {
            const float od = __shfl_xor(bd, off);
            const int   on = __shfl_xor(bn, off);
            if (od > bd || (od == bd && on < bn)) { bd = od; bn = on; }
        }
        // ---- per-wave publish: slot (blk*8 + wid), no barrier needed ----
        u64* base = slots + ((size_t)((t & 1) * BATCH + b)) * (64 * SSTRIDE);
        if (lane == 0) {
            const u64 v = ((u64)__float_as_uint(bd) << 32)
                        | ((u64)(t & 1023) << 15) | (u64)bn;
            AT_ST(base + (blk * NWAVE + wid) * SSTRIDE, v);
        }

        int gw;
        if (wid == 0) {
            // ---- wave0: poll ALL 64 slots, lane L <-> slot L (4-deep) ----
            u64* sp = base + lane * SSTRIDE;
            u64 v;
            for (;;) {
                const u64 v0 = AT_LD(sp);
                const u64 v1 = AT_LD(sp);
                const u64 v2 = AT_LD(sp);
                const u64 v3 = AT_LD(sp);
                if (__all(TAG(v0) == t)) { v = v0; break; }
                if (__all(TAG(v1) == t)) { v = v1; break; }
                if (__all(TAG(v2) == t)) { v = v2; break; }
                if (__all(TAG(v3) == t)) { v = v3; break; }
            }
            // ---- winner over 64 slot-lanes (max d, tie -> min n) ----
            float od = __uint_as_float((unsigned)(v >> 32));
            int   on = (int)(v & 32767);
#pragma unroll
            for (int off = 32; off >= 1; off >>= 1) {
                const float pd = __shfl_xor(od, off);
                const int   pn = __shfl_xor(on, off);
                if (pd > od || (pd == od && pn < on)) { od = pd; on = pn; }
            }
            // ---- LDS release: {t | winner} ----
            if (lane == 0) {
                LDS_ST(&swin, ((u64)(unsigned)t << 32) | (unsigned)on);
                if (blk == 0) idxbuf[(size_t)b * KSEL + t] = on;
            }
            gw = __builtin_amdgcn_readfirstlane(on);
        } else {
            // ---- other waves: spin on the LDS flag (intra-CU, cheap) ----
            u64 w;
            do { w = LDS_LD(&swin); } while ((int)(w >> 32) != t);
            gw = __builtin_amdgcn_readfirstlane((int)(w & 0xFFFFFFFFu));
        }
        // scalar (SGPR) center fetch of read-only data (hot in L1/L2)
        cx = Xp[gw]; cy = Yp[gw]; cz = Zp[gw];
    }
}

__global__ void gather_kernel(const float* __restrict__ xyz,
                              const float* __restrict__ feat,
                              const int* __restrict__ idxbuf,
                              float* __restrict__ out) {
    const int SN = BATCH * 3 * KSEL;                  // 24576
    const int total = SN + BATCH * CFEAT * KSEL;      // 1073152
    const int i = blockIdx.x * blockDim.x + threadIdx.x;
    if (i >= total) return;
    if (i < SN) {
        const int b = i / (3 * KSEL);
        const int r = i - b * 3 * KSEL;
        const int c = r / KSEL;
        const int k = r - c * KSEL;
        const int n = idxbuf[b * KSEL + k];
        out[i] = xyz[((size_t)b * 3 + c) * NPTS + n];
    } else {
        const int i2 = i - SN;
        const int b = i2 / (CFEAT * KSEL);
        const int r = i2 - b * CFEAT * KSEL;
        const int c = r / KSEL;
        const int k = r - c * KSEL;
        const int n = idxbuf[b * KSEL + k];
        out[SN + i2] = feat[((size_t)b * CFEAT + c) * NPTS + n];
    }
}

extern "C" void kernel_launch(void* const* d_in, const int* in_sizes, int n_in,
                              void* d_out, int out_size, void* d_ws, size_t ws_size,
                              hipStream_t stream) {
    const float* xyz  = (const float*)d_in[0];
    const float* feat = (const float*)d_in[1];
    float* out = (float*)d_out;
    char* ws = (char*)d_ws;
    // ws layout: [0,32KB) idxbuf | [32KB, +32KB) u64 slots [2][8][64][SSTRIDE]

    // zero slot tags every call (tag 0 never matches t>=1) — replay-safe
    hipMemsetAsync(ws + 32768, 0, 2 * BATCH * 64 * SSTRIDE * sizeof(u64), stream);

    void* args[] = {(void*)&xyz, (void*)&ws};
    hipLaunchCooperativeKernel((const void*)fps_kernel,
                               dim3(BATCH * WPB), dim3(TPB), args, 0, stream);

    int* idxbuf = (int*)d_ws;
    const int total = BATCH * 3 * KSEL + BATCH * CFEAT * KSEL;  // 1073152
    gather_kernel<<<(total + 255) / 256, 256, 0, stream>>>(xyz, feat, idxbuf, out);
}

// Round 15
// 2396.908 us; speedup vs baseline: 1.1813x; 1.0287x over previous
//
#include <hip/hip_runtime.h>

// Pool_FPS: furthest point sampling (B=8, N=32768, K=1024) + gather (C=128).
// FINAL-FORM (= R10, measured best 2406us): 8 worker blocks/batch (coop
// launch), block-level u64 slot protocol at agent scope, wave0-only 4-deep
// poll, one barrier pair per iteration.
//
// SESSION VERDICT (R9-R14): six sync-protocol variants all land at
// 2.25-2.8us/iter -> the floor is 2 sequential agent(LLC)-scope round trips
// per strictly-sequential iteration (store-visible + poll-detect + straggler
// spread ~= 1.9us) + 0.35us compute. Not memory- or compute-bound (VALUBusy
// ~5%, HBM ~0.2%): latency-bound on the IF coherence point. Alternatives
// disproved: single-block/batch = 4.6us/iter (VGPR/LDS-capped, R1-R5);
// sc0/wg-scope "XCD-local" rendezvous unsound (R8 deadlock, R12/R13 stale).
//
// Protocol (bit-exact R7-R14): u64 [d:32|tag:10|n:15] parity slots, relaxed
// agent atomics, tag==t proves freshness, no fences; publish(t) overwrites
// own t-2 slot only after all passed detect(t-1) - single-writer race-free.
// Exactness: d = ((dx*dx+dy*dy)+dz*dz), rn ops, no fma contraction; argmax
// tie-break = smallest global index at every reduce level. idx[0]=0.
// Replay-safe: slot tags zeroed via hipMemsetAsync each launch.

#define BATCH 8
#define NPTS 32768
#define KSEL 1024
#define CFEAT 128
#define WPB 8                    // worker blocks per batch
#define LOCN (NPTS / WPB)        // 4096 points per block
#define TPB 512                  // 8 points per thread
#define PPT 8
#define NWAVE (TPB / 64)         // 8 waves

typedef unsigned long long u64;

#define AT_ST(p, v) __hip_atomic_store((p), (v), __ATOMIC_RELAXED, __HIP_MEMORY_SCOPE_AGENT)
#define AT_LD(p)    __hip_atomic_load((p), __ATOMIC_RELAXED, __HIP_MEMORY_SCOPE_AGENT)
#define TAG(v)      ((int)(((v) >> 15) & 1023))

__global__ void
__attribute__((amdgpu_flat_work_group_size(TPB, TPB)))
fps_kernel(const float* __restrict__ xyz, char* __restrict__ ws) {
    int* idxbuf = (int*)ws;                     // [BATCH*KSEL] 32KB
    u64* slots  = (u64*)(ws + 32768);           // [2][BATCH][WPB] parity slot sets

    __shared__ float swd[NWAVE];
    __shared__ int   swn[NWAVE];
    __shared__ int   sgw;

    const int bid  = blockIdx.x;
    const int b    = bid & 7;                   // batch
    const int blk  = bid >> 3;                  // worker id within batch
    const int tid  = threadIdx.x;
    const int lane = tid & 63;
    const int wid  = tid >> 6;

    const float* Xp = xyz + (size_t)b * 3 * NPTS;
    const float* Yp = Xp + NPTS;
    const float* Zp = Xp + 2 * NPTS;
    const float4* X4 = (const float4*)Xp;
    const float4* Y4 = (const float4*)Yp;
    const float4* Z4 = (const float4*)Zp;

    // own 8 consecutive points: global idx = blk*LOCN + tid*8 + e
    const int f4 = blk * (LOCN / 4) + 2 * tid;
    const float4 xa = X4[f4], xb = X4[f4 + 1];
    const float4 ya = Y4[f4], yb = Y4[f4 + 1];
    const float4 za = Z4[f4], zb = Z4[f4 + 1];
    float xs[PPT] = {xa.x, xa.y, xa.z, xa.w, xb.x, xb.y, xb.z, xb.w};
    float ys[PPT] = {ya.x, ya.y, ya.z, ya.w, yb.x, yb.y, yb.z, yb.w};
    float zs[PPT] = {za.x, za.y, za.z, za.w, zb.x, zb.y, zb.z, zb.w};
    float ds[PPT];
#pragma unroll
    for (int e = 0; e < PPT; ++e) ds[e] = __builtin_inff();

    if (blk == 0 && tid == 0) idxbuf[(size_t)b * KSEL] = 0;   // idx[0] = 0
    float cx = Xp[0], cy = Yp[0], cz = Zp[0];

    for (int t = 1; t < KSEL; ++t) {
        // ---- update ds, thread-local argmax (8 pts, all in regs) ----
        float bd = -__builtin_inff();
        int   be = 0;
#pragma unroll
        for (int e = 0; e < PPT; ++e) {
            const float dx = xs[e] - cx;
            const float dy = ys[e] - cy;
            const float dz = zs[e] - cz;
            // exact: ((dx*dx + dy*dy) + dz*dz), rn, no fma contraction
            const float d = __fadd_rn(__fadd_rn(__fmul_rn(dx, dx), __fmul_rn(dy, dy)),
                                      __fmul_rn(dz, dz));
            const float nd = fminf(ds[e], d);
            ds[e] = nd;
            const bool gt = nd > bd;        // strict > keeps smallest e
            bd = gt ? nd : bd;
            be = gt ? e : be;
        }
        int bn = tid * PPT + be;            // block-local point index (0..4095)
        // ---- wave argmax (max d, tie -> min index) ----
#pragma unroll
        for (int off = 32; off >= 1; off >>= 1) {
            const float od = __shfl_xor(bd, off);
            const int   on = __shfl_xor(bn, off);
            if (od > bd || (od == bd && on < bn)) { bd = od; bn = on; }
        }
        if (lane == 0) { swd[wid] = bd; swn[wid] = bn; }
        __syncthreads();                    // barrier #1

        if (wid == 0) {
            // ---- block reduce over 8 wave slots (dup-safe: lane&7) ----
            float rd = swd[lane & 7];
            int   rn = swn[lane & 7];
#pragma unroll
            for (int off = 4; off >= 1; off >>= 1) {
                const float od = __shfl_xor(rd, off);
                const int   on = __shfl_xor(rn, off);
                if (od > rd || (od == rd && on < rn)) { rd = od; rn = on; }
            }
            u64* slotbase = &slots[(size_t)(t & 1) * (BATCH * WPB) + b * WPB];
            if (lane == 0) {
                const int gn = blk * LOCN + rn;          // batch-global index
                const u64 v = ((u64)__float_as_uint(rd) << 32)
                            | ((u64)(t & 1023) << 15) | (u64)gn;
                AT_ST(&slotbase[blk], v);
            }
            // ---- 4-deep pipelined poll (tag==t => fresh; any-hit exit) ----
            u64* sp = &slotbase[lane & 7];
            u64 v;
            for (;;) {
                const u64 v0 = AT_LD(sp);
                const u64 v1 = AT_LD(sp);
                const u64 v2 = AT_LD(sp);
                const u64 v3 = AT_LD(sp);
                if (__all(TAG(v0) == t)) { v = v0; break; }
                if (__all(TAG(v1) == t)) { v = v1; break; }
                if (__all(TAG(v2) == t)) { v = v2; break; }
                if (__all(TAG(v3) == t)) { v = v3; break; }
            }
            // ---- reduce the 8 partials (period 8 -> bfly 4,2,1) ----
            float od = __uint_as_float((unsigned)(v >> 32));
            int   on = (int)(v & 32767);
#pragma unroll
            for (int off = 4; off >= 1; off >>= 1) {
                const float pd = __shfl_xor(od, off);
                const int   pn = __shfl_xor(on, off);
                if (pd > od || (pd == od && pn < on)) { od = pd; on = pn; }
            }
            if (lane == 0) sgw = on;
        }
        __syncthreads();                    // barrier #2
        const int gw = sgw;
        if (blk == 0 && tid == 0) idxbuf[(size_t)b * KSEL + t] = gw;
        // scalar (SGPR) center fetch of read-only data (L1/L2 cached)
        cx = Xp[gw]; cy = Yp[gw]; cz = Zp[gw];
    }
}

__global__ void gather_kernel(const float* __restrict__ xyz,
                              const float* __restrict__ feat,
                              const int* __restrict__ idxbuf,
                              float* __restrict__ out) {
    const int SN = BATCH * 3 * KSEL;                  // 24576
    const int total = SN + BATCH * CFEAT * KSEL;      // 1073152
    const int i = blockIdx.x * blockDim.x + threadIdx.x;
    if (i >= total) return;
    if (i < SN) {
        const int b = i / (3 * KSEL);
        const int r = i - b * 3 * KSEL;
        const int c = r / KSEL;
        const int k = r - c * KSEL;
        const int n = idxbuf[b * KSEL + k];
        out[i] = xyz[((size_t)b * 3 + c) * NPTS + n];
    } else {
        const int i2 = i - SN;
        const int b = i2 / (CFEAT * KSEL);
        const int r = i2 - b * CFEAT * KSEL;
        const int c = r / KSEL;
        const int k = r - c * KSEL;
        const int n = idxbuf[b * KSEL + k];
        out[SN + i2] = feat[((size_t)b * CFEAT + c) * NPTS + n];
    }
}

extern "C" void kernel_launch(void* const* d_in, const int* in_sizes, int n_in,
                              void* d_out, int out_size, void* d_ws, size_t ws_size,
                              hipStream_t stream) {
    const float* xyz  = (const float*)d_in[0];
    const float* feat = (const float*)d_in[1];
    float* out = (float*)d_out;
    char* ws = (char*)d_ws;
    // ws layout: [0,32KB) idxbuf | [32KB, +1KB) u64 slots [2][8][8]

    // zero the slot tags every call (tag 0 never matches t>=1) — replay-safe
    hipMemsetAsync(ws + 32768, 0, 2 * BATCH * WPB * sizeof(u64), stream);

    void* args[] = {(void*)&xyz, (void*)&ws};
    hipLaunchCooperativeKernel((const void*)fps_kernel,
                               dim3(BATCH * WPB), dim3(TPB), args, 0, stream);

    int* idxbuf = (int*)d_ws;
    const int total = BATCH * 3 * KSEL + BATCH * CFEAT * KSEL;  // 1073152
    gather_kernel<<<(total + 255) / 256, 256, 0, stream>>>(xyz, feat, idxbuf, out);
}